// Round 12
// baseline (337.909 us; speedup 1.0000x reference)
//
#include <hip/hip_runtime.h>
#include <stdint.h>

#define KD 4096
#define ND 4096
#define BK 64
#define NT 64            // K tiles (= HQQ groups along K: GROUP_SIZE == BK)

typedef __bf16 bf16x8 __attribute__((ext_vector_type(8)));
typedef float f32x4 __attribute__((ext_vector_type(4)));

#define BAR()  asm volatile("s_barrier" ::: "memory")
#define LGKM0() do { asm volatile("s_waitcnt lgkmcnt(0)" ::: "memory"); \
                     __builtin_amdgcn_sched_barrier(0); } while (0)
#define VM0()  do { asm volatile("s_waitcnt vmcnt(0)" ::: "memory"); \
                     __builtin_amdgcn_sched_barrier(0); } while (0)

// ---------------------------------------------------------------------------
// Fully fused HQQ-int4 linear: one kernel. Each block stages x (fp32) and
// W_q (int32 packed bytes) straight from HBM, converts/dequants in-register,
// ds_writes bf16 tiles into LDS, MFMAs. No Wb/xb intermediates (saves ~25us
// of pure HBM prep + 2 launches vs R11).
// Geometry: 256x256 tile, BK=64, 8 waves (2Mx4N of 128x64), 512 thr.
// LDS [buf][mat][kh][256][32] bf16 = 128 KiB, verified slot-XOR mapping:
//   LDS[row][slot] = global[row][slot ^ ((row>>1)&3)], read sx=ls^((lr>>1)&3)
// (identical algebra to R9/R11 which measured 0 bank conflicts; write-side
// bank math: 4 lanes/bank * 4B = minimum cycles, conflict-free.)
// Dequant: o = bn0+row; o<2048 -> high nibble of Wq[o*4096+k], else low of
// Wq[(o-2048)*4096+k]; g = o*64 + kt; w = (nib - z)*s = fma(nib, s, -z*s).
// Schedule/tile: issue 18 loads(t+1); RD kh0 (12); LGKM0; MFQ0; RD kh1 (12);
// VM0 (loads ~800cyc deep); cvt+dequant+8 ds_write; LGKM0; MFQ1; BAR.
// WAR safe: writes target opposite buffer, last read before previous BAR.
// ---------------------------------------------------------------------------
#define RGN(BUF, MAT, KH) ((((BUF) * 2 + (MAT)) * 2 + (KH)) * 8192)

#define RD_A(P, KH) do {                                                              \
    const uint16_t* _r = lds + RGN(P, 0, KH);                                         \
    _Pragma("unroll")                                                                 \
    for (int m = 0; m < 8; ++m)                                                       \
        a[m] = *(const bf16x8*)&_r[(wr * 128 + m * 16 + lr) * 32 + sx * 8];           \
} while (0)

#define RD_B(P, KH) do {                                                              \
    const uint16_t* _r = lds + RGN(P, 1, KH);                                         \
    _Pragma("unroll")                                                                 \
    for (int n = 0; n < 4; ++n)                                                       \
        b[n] = *(const bf16x8*)&_r[(wc * 64 + n * 16 + lr) * 32 + sx * 8];            \
} while (0)

#define MFQ() do {                                                                    \
    __builtin_amdgcn_s_setprio(1);                                                    \
    _Pragma("unroll")                                                                 \
    for (int m = 0; m < 8; ++m)                                                       \
    _Pragma("unroll")                                                                 \
    for (int n = 0; n < 4; ++n)                                                       \
        acc[m][n] = __builtin_amdgcn_mfma_f32_16x16x32_bf16(                          \
            a[m], b[n], acc[m][n], 0, 0, 0);                                          \
    __builtin_amdgcn_s_setprio(0);                                                    \
} while (0)

#define LOAD_AB(KT) do {                                                              \
    const float4* _xp = (const float4*)(xp + (size_t)(KT) * BK);                      \
    _Pragma("unroll")                                                                 \
    for (int j = 0; j < 8; ++j) ax[j] = _xp[j];                                       \
    const int4* _wp = (const int4*)(wp + (size_t)(KT) * BK);                          \
    _Pragma("unroll")                                                                 \
    for (int j = 0; j < 8; ++j) bx[j] = _wp[j];                                       \
    sv = scale[g0 + (KT)];                                                            \
    zv = zero[g0 + (KT)];                                                             \
} while (0)

#define CVT_WRITE(Q) do {                                                             \
    uint16_t* _dA = lds + RGN(Q, 0, skh) + srow * 32;                                 \
    _Pragma("unroll")                                                                 \
    for (int j = 0; j < 4; ++j) {                                                     \
        bf16x8 v;                                                                     \
        v[0] = (__bf16)ax[2*j].x;   v[1] = (__bf16)ax[2*j].y;                         \
        v[2] = (__bf16)ax[2*j].z;   v[3] = (__bf16)ax[2*j].w;                         \
        v[4] = (__bf16)ax[2*j+1].x; v[5] = (__bf16)ax[2*j+1].y;                       \
        v[6] = (__bf16)ax[2*j+1].z; v[7] = (__bf16)ax[2*j+1].w;                       \
        *(bf16x8*)&_dA[(j ^ swz) * 8] = v;                                            \
    }                                                                                 \
    float _s = sv, _nzs = -zv * sv;                                                   \
    uint16_t* _dB = lds + RGN(Q, 1, skh) + srow * 32;                                 \
    _Pragma("unroll")                                                                 \
    for (int j = 0; j < 4; ++j) {                                                     \
        int4 p0 = bx[2*j], p1 = bx[2*j+1];                                            \
        bf16x8 v;                                                                     \
        v[0] = (__bf16)fmaf((float)((p0.x >> shift) & 15), _s, _nzs);                 \
        v[1] = (__bf16)fmaf((float)((p0.y >> shift) & 15), _s, _nzs);                 \
        v[2] = (__bf16)fmaf((float)((p0.z >> shift) & 15), _s, _nzs);                 \
        v[3] = (__bf16)fmaf((float)((p0.w >> shift) & 15), _s, _nzs);                 \
        v[4] = (__bf16)fmaf((float)((p1.x >> shift) & 15), _s, _nzs);                 \
        v[5] = (__bf16)fmaf((float)((p1.y >> shift) & 15), _s, _nzs);                 \
        v[6] = (__bf16)fmaf((float)((p1.z >> shift) & 15), _s, _nzs);                 \
        v[7] = (__bf16)fmaf((float)((p1.w >> shift) & 15), _s, _nzs);                 \
        *(bf16x8*)&_dB[(j ^ swz) * 8] = v;                                            \
    }                                                                                 \
} while (0)

__global__ __launch_bounds__(512, 2)
void fused_kernel(const float* __restrict__ x,
                  const int* __restrict__ Wq,
                  const float* __restrict__ scale,
                  const float* __restrict__ zero,
                  float* __restrict__ C) {
    __shared__ uint16_t lds[65536];   // 128 KiB: [2 buf][2 mat][2 kh][256][32]

    const int tid  = threadIdx.x;
    const int wave = tid >> 6;
    const int lane = tid & 63;
    const int wr = wave >> 2;                  // 0..1 (M)
    const int wc = wave & 3;                   // 0..3 (N)
    const int lr = lane & 15;
    const int ls = lane >> 4;
    const int sx = ls ^ ((lr >> 1) & 3);       // verified read swizzle

    // XCD-aware swizzle: 256 wgs, 8 XCDs, 32 contiguous tiles per XCD
    int bid = blockIdx.x;
    int wg = (bid & 7) * 32 + (bid >> 3);
    const int bm0 = (wg >> 4) * 256;
    const int bn0 = (wg & 15) * 256;

    // staging coords: thread covers row srow, k-halftile skh, 32 cols
    const int srow = tid >> 1;                 // 0..255
    const int skh  = tid & 1;                  // kh region
    const int sc0  = skh * 32;                 // col base within BK
    const int swz  = (srow >> 1) & 3;          // write slot XOR
    const int shift = (bn0 < 2048) ? 4 : 0;    // high/low nibble (block-uniform)
    const int wrow = (bn0 + srow) & 2047;

    const float* xp = x + (size_t)(bm0 + srow) * KD + sc0;
    const int*   wp = Wq + (size_t)wrow * KD + sc0;
    const int    g0 = (bn0 + srow) * 64;       // HQQ group base (g = g0 + kt)

    f32x4 acc[8][4];
#pragma unroll
    for (int m = 0; m < 8; ++m)
#pragma unroll
        for (int n = 0; n < 4; ++n) {
            f32x4 z = {0.f, 0.f, 0.f, 0.f};
            acc[m][n] = z;
        }

    bf16x8 a[8], b[4];
    float4 ax[8];
    int4   bx[8];
    float  sv, zv;

    // prologue: tile 0 -> buf 0
    LOAD_AB(0);
    VM0();
    CVT_WRITE(0);
    LGKM0();
    BAR();

#pragma unroll 1
    for (int t = 0; t < NT - 1; ++t) {          // tiles 0..62 (tail = 63)
        const int p = t & 1, q = p ^ 1;
        LOAD_AB(t + 1);                         // 18 vmem, land during MFQ0
        RD_A(p, 0); RD_B(p, 0);                 // 12 ds_read
        LGKM0();
        MFQ();                                  // kh0: 32 MFMA
        RD_A(p, 1); RD_B(p, 1);                 // kh1 reads complete under VALU
        VM0();                                  // loads ~800 cyc deep
        CVT_WRITE(q);                           // cvt + dequant + 8 ds_write
        LGKM0();                                // kh1 reads + all writes done
        MFQ();                                  // kh1: 32 MFMA
        BAR();                                  // q complete/visible; WAR safe
    }
    // tail tile 63 (buf 1): reads only
    {
        RD_A(1, 0); RD_B(1, 0);
        LGKM0();
        MFQ();
        RD_A(1, 1); RD_B(1, 1);
        LGKM0();
        MFQ();
    }

    // epilogue: D layout col=lane&15, row=(lane>>4)*4+r  [m89/m91]
    const int r0 = ls * 4;
#pragma unroll
    for (int m = 0; m < 8; ++m)
#pragma unroll
        for (int n = 0; n < 4; ++n)
#pragma unroll
            for (int r = 0; r < 4; ++r) {
                int row = bm0 + wr * 128 + m * 16 + r0 + r;
                int col = bn0 + wc * 64 + n * 16 + lr;
                C[(size_t)row * ND + col] = acc[m][n][r];
            }
}

extern "C" void kernel_launch(void* const* d_in, const int* in_sizes, int n_in,
                              void* d_out, int out_size, void* d_ws, size_t ws_size,
                              hipStream_t stream) {
    const float* x     = (const float*)d_in[0];
    const int*   Wq    = (const int*)d_in[1];   // uint8 pushed as int32
    const float* scale = (const float*)d_in[2];
    const float* zero  = (const float*)d_in[3];
    float* out = (float*)d_out;

    hipLaunchKernelGGL(fused_kernel, dim3(256), dim3(512), 0, stream,
                       x, Wq, scale, zero, out);
}

// Round 13
// 243.202 us; speedup vs baseline: 1.3894x; 1.3894x over previous
//
#include <hip/hip_runtime.h>
#include <stdint.h>

#define KD 4096
#define ND 4096
#define BK 64
#define NT 64            // K tiles

typedef __bf16 bf16x8 __attribute__((ext_vector_type(8)));
typedef float f32x4 __attribute__((ext_vector_type(4)));

__device__ __forceinline__ uint32_t f32_to_bf16(float f) {
    union { float f; uint32_t u; } v; v.f = f;
    return (v.u + 0x7FFFu + ((v.u >> 16) & 1u)) >> 16;
}

#define GLDS16(gp, lp) \
    __builtin_amdgcn_global_load_lds((const __attribute__((address_space(1))) void*)(gp), \
                                     (__attribute__((address_space(3))) void*)(lp), 16, 0, 0)

// ---------------------------------------------------------------------------
// Dequant W_q (int32-widened packed bytes) -> bf16 Wb[4096][4096] (B^T).
// Kept separate (R12 lesson: fusing W-dequant puts a stride-256B scale/zero
// gather on the GEMM critical path; also int32 source is 2x the bytes of bf16).
// ---------------------------------------------------------------------------
__global__ void dq_kernel(const int* __restrict__ Wq,
                          const float* __restrict__ scale,
                          const float* __restrict__ zero,
                          uint16_t* __restrict__ Wb) {
    int t = blockIdx.x * 256 + threadIdx.x;
    int o  = t >> 9;
    int i0 = (t & 511) << 3;
    const uint4* wp = (const uint4*)Wq;
    uint4 pa = wp[t * 2], pb = wp[t * 2 + 1];
    uint32_t v[8] = {pa.x, pa.y, pa.z, pa.w, pb.x, pb.y, pb.z, pb.w};
    int gh = (o << 6) + (i0 >> 6);
    int gl = gh + (2048 << 6);
    float sh = scale[gh], zh = zero[gh];
    float sl = scale[gl], zl = zero[gl];
    uint32_t hw[4], lw[4];
#pragma unroll
    for (int p = 0; p < 4; ++p) {
        uint32_t b0 = v[p * 2], b1 = v[p * 2 + 1];
        uint32_t h0 = f32_to_bf16(((float)((b0 >> 4) & 15u) - zh) * sh);
        uint32_t h1 = f32_to_bf16(((float)((b1 >> 4) & 15u) - zh) * sh);
        uint32_t l0 = f32_to_bf16(((float)(b0 & 15u) - zl) * sl);
        uint32_t l1 = f32_to_bf16(((float)(b1 & 15u) - zl) * sl);
        hw[p] = h0 | (h1 << 16);
        lw[p] = l0 | (l1 << 16);
    }
    uint4 hv = {hw[0], hw[1], hw[2], hw[3]};
    uint4 lv = {lw[0], lw[1], lw[2], lw[3]};
    *(uint4*)&Wb[(size_t)o * KD + i0]          = hv;
    *(uint4*)&Wb[(size_t)(o + 2048) * KD + i0] = lv;
}

// ---------------------------------------------------------------------------
// GEMM with fused x-convert (xc kernel eliminated): 256x256 tile, BK=64,
// 8 waves (2Mx4N of 128x64), 512 thr, LDS 128 KiB dbuf.
// A staged from fp32 x in registers: thread t covers row=t>>1, kh=t&1,
// 32 floats (8 float4) -> cvt -> 4 ds_write_b128 at slots j^swz (balanced
// across all 8 row-parity x slot bank groups => conflict-free).
// B staged async via gload_lds from Wb (pre-swizzled source, linear dest).
// One barrier/tile: issue ax loads + all 4 B gloads; read kh0 frags; MFQ0;
// read kh1 frags; VM(0) (loads ~1 cluster deep, LLC-resident); cvt+write A;
// LGKM0; MFQ1; BAR. WAR safe: q last read before previous tile-end BAR.
// Swizzle identical algebra to R9/R11 (measured 0 conflicts).
// ---------------------------------------------------------------------------
#define BAR()  asm volatile("s_barrier" ::: "memory")
#define LGKM0() do { asm volatile("s_waitcnt lgkmcnt(0)" ::: "memory"); \
                     __builtin_amdgcn_sched_barrier(0); } while (0)
#define VM0()  do { asm volatile("s_waitcnt vmcnt(0)" ::: "memory"); \
                     __builtin_amdgcn_sched_barrier(0); } while (0)

#define RGN(BUF, MAT, KH) ((((BUF) * 2 + (MAT)) * 2 + (KH)) * 8192)

#define STAGE_B(Q, KH, KB) do {                                                       \
    GLDS16(Bg + (size_t)(tid >> 2) * KD + (KB) + (KH) * 32 + sslot * 8,               \
           lds + RGN(Q, 1, KH) + tid * 8);                                            \
    GLDS16(Bg + (size_t)(128 + (tid >> 2)) * KD + (KB) + (KH) * 32 + sslot * 8,       \
           lds + RGN(Q, 1, KH) + 4096 + tid * 8);                                     \
} while (0)

#define AXLOAD(KT) do {                                                               \
    const float4* _xp = (const float4*)(xp + (size_t)(KT) * BK);                      \
    _Pragma("unroll")                                                                 \
    for (int j = 0; j < 8; ++j) ax[j] = _xp[j];                                       \
} while (0)

#define CVT_WRITE_A(Q) do {                                                           \
    uint16_t* _d = lds + RGN(Q, 0, akh) + arow * 32;                                  \
    _Pragma("unroll")                                                                 \
    for (int j = 0; j < 4; ++j) {                                                     \
        bf16x8 v;                                                                     \
        v[0] = (__bf16)ax[2*j].x;   v[1] = (__bf16)ax[2*j].y;                         \
        v[2] = (__bf16)ax[2*j].z;   v[3] = (__bf16)ax[2*j].w;                         \
        v[4] = (__bf16)ax[2*j+1].x; v[5] = (__bf16)ax[2*j+1].y;                       \
        v[6] = (__bf16)ax[2*j+1].z; v[7] = (__bf16)ax[2*j+1].w;                       \
        *(bf16x8*)&_d[(j ^ aswz) * 8] = v;                                            \
    }                                                                                 \
} while (0)

#define RD_A(P, KH) do {                                                              \
    const uint16_t* _r = lds + RGN(P, 0, KH);                                         \
    _Pragma("unroll")                                                                 \
    for (int m = 0; m < 8; ++m)                                                       \
        a[m] = *(const bf16x8*)&_r[(wr * 128 + m * 16 + lr) * 32 + sx * 8];           \
} while (0)

#define RD_B(P, KH) do {                                                              \
    const uint16_t* _r = lds + RGN(P, 1, KH);                                         \
    _Pragma("unroll")                                                                 \
    for (int n = 0; n < 4; ++n)                                                       \
        b[n] = *(const bf16x8*)&_r[(wc * 64 + n * 16 + lr) * 32 + sx * 8];            \
} while (0)

#define MFQ() do {                                                                    \
    __builtin_amdgcn_s_setprio(1);                                                    \
    _Pragma("unroll")                                                                 \
    for (int m = 0; m < 8; ++m)                                                       \
    _Pragma("unroll")                                                                 \
    for (int n = 0; n < 4; ++n)                                                       \
        acc[m][n] = __builtin_amdgcn_mfma_f32_16x16x32_bf16(                          \
            a[m], b[n], acc[m][n], 0, 0, 0);                                          \
    __builtin_amdgcn_s_setprio(0);                                                    \
} while (0)

__global__ __launch_bounds__(512, 2)
void gemm_kernel(const float* __restrict__ x,
                 const uint16_t* __restrict__ B,
                 float* __restrict__ C) {
    __shared__ uint16_t lds[65536];   // 128 KiB: [2 buf][2 mat][2 kh][256][32]

    const int tid  = threadIdx.x;
    const int wave = tid >> 6;
    const int lane = tid & 63;
    const int wr = wave >> 2;                  // 0..1 (M)
    const int wc = wave & 3;                   // 0..3 (N)
    const int lr = lane & 15;
    const int ls = lane >> 4;
    const int sx = ls ^ ((lr >> 1) & 3);              // verified read swizzle
    const int sslot = (tid & 3) ^ ((tid >> 3) & 3);   // B source pre-swizzle

    // A staging coords
    const int arow = tid >> 1;                 // 0..255
    const int akh  = tid & 1;
    const int aswz = (arow >> 1) & 3;

    // XCD-aware swizzle: 256 wgs, 8 XCDs, 32 contiguous tiles per XCD
    int bid = blockIdx.x;
    int wg = (bid & 7) * 32 + (bid >> 3);
    const int bm0 = (wg >> 4) * 256;
    const int bn0 = (wg & 15) * 256;

    const float*    xp = x + (size_t)(bm0 + arow) * KD + akh * 32;
    const uint16_t* Bg = B + (size_t)bn0 * KD;

    f32x4 acc[8][4];
#pragma unroll
    for (int m = 0; m < 8; ++m)
#pragma unroll
        for (int n = 0; n < 4; ++n) {
            f32x4 z = {0.f, 0.f, 0.f, 0.f};
            acc[m][n] = z;
        }

    bf16x8 a[8], b[4];
    float4 ax[8];

    // prologue: tile 0 -> buf 0
    AXLOAD(0);
    STAGE_B(0, 0, 0);
    STAGE_B(0, 1, 0);
    VM0();
    CVT_WRITE_A(0);
    LGKM0();
    BAR();

#pragma unroll 1
    for (int t = 0; t < NT - 1; ++t) {          // tiles 0..62 (tail = 63)
        const int p = t & 1, q = p ^ 1;
        const int kn = (t + 1) * BK;
        AXLOAD(t + 1);                          // 8 float4
        STAGE_B(q, 0, kn);                      // 4 gload_lds total
        STAGE_B(q, 1, kn);
        RD_A(p, 0); RD_B(p, 0);                 // 12 ds_read
        LGKM0();
        MFQ();                                  // kh0: 32 MFMA
        RD_A(p, 1); RD_B(p, 1);
        VM0();                                  // ax + B-gloads home (deep)
        CVT_WRITE_A(q);                         // cvt + 4 ds_write_b128
        LGKM0();                                // kh1 reads + writes home
        MFQ();                                  // kh1: 32 MFMA
        BAR();                                  // q complete & visible
    }
    // tail tile 63 (buf 1): reads only
    {
        RD_A(1, 0); RD_B(1, 0);
        LGKM0();
        MFQ();
        RD_A(1, 1); RD_B(1, 1);
        LGKM0();
        MFQ();
    }

    // epilogue: D layout col=lane&15, row=(lane>>4)*4+r  [m89/m91]
    const int r0 = ls * 4;
#pragma unroll
    for (int m = 0; m < 8; ++m)
#pragma unroll
        for (int n = 0; n < 4; ++n)
#pragma unroll
            for (int r = 0; r < 4; ++r) {
                int row = bm0 + wr * 128 + m * 16 + r0 + r;
                int col = bn0 + wc * 64 + n * 16 + lr;
                C[(size_t)row * ND + col] = acc[m][n][r];
            }
}

extern "C" void kernel_launch(void* const* d_in, const int* in_sizes, int n_in,
                              void* d_out, int out_size, void* d_ws, size_t ws_size,
                              hipStream_t stream) {
    const float* x     = (const float*)d_in[0];
    const int*   Wq    = (const int*)d_in[1];   // uint8 pushed as int32
    const float* scale = (const float*)d_in[2];
    const float* zero  = (const float*)d_in[3];
    float* out = (float*)d_out;

    uint16_t* Wb = (uint16_t*)d_ws;             // 32 MB

    hipLaunchKernelGGL(dq_kernel, dim3(4096), dim3(256), 0, stream, Wq, scale, zero, Wb);
    hipLaunchKernelGGL(gemm_kernel, dim3(256), dim3(512), 0, stream, x, Wb, out);
}

// Round 14
// 151.434 us; speedup vs baseline: 2.2314x; 1.6060x over previous
//
#include <hip/hip_runtime.h>
#include <stdint.h>

#define MD 4096
#define ND 4096
#define KD 4096
#define BK 64
#define NT (KD / BK)   // 64 K-tiles

typedef __bf16 bf16x8 __attribute__((ext_vector_type(8)));
typedef float f32x4 __attribute__((ext_vector_type(4)));

__device__ __forceinline__ uint32_t f32_to_bf16(float f) {
    union { float f; uint32_t u; } v; v.f = f;
    return (v.u + 0x7FFFu + ((v.u >> 16) & 1u)) >> 16;
}

#define GLDS16(gp, lp) \
    __builtin_amdgcn_global_load_lds((const __attribute__((address_space(1))) void*)(gp), \
                                     (__attribute__((address_space(3))) void*)(lp), 16, 0, 0)

// ---------------------------------------------------------------------------
// Dequant W_q (int32-widened packed bytes) -> bf16 Wb (B^T). Separate kernel
// (R12/R13: fusing dequant or x-convert into the GEMM regresses badly —
// scale/zero gathers + reg-staged ds_writes serialize on the MFMA path).
// ---------------------------------------------------------------------------
__global__ void dq_kernel(const int* __restrict__ Wq,
                          const float* __restrict__ scale,
                          const float* __restrict__ zero,
                          uint16_t* __restrict__ Wb) {
    int t = blockIdx.x * 256 + threadIdx.x;
    int o  = t >> 9;
    int i0 = (t & 511) << 3;
    const uint4* wp = (const uint4*)Wq;
    uint4 pa = wp[t * 2], pb = wp[t * 2 + 1];
    uint32_t v[8] = {pa.x, pa.y, pa.z, pa.w, pb.x, pb.y, pb.z, pb.w};
    int gh = (o << 6) + (i0 >> 6);
    int gl = gh + (2048 << 6);
    float sh = scale[gh], zh = zero[gh];
    float sl = scale[gl], zl = zero[gl];
    uint32_t hw[4], lw[4];
#pragma unroll
    for (int p = 0; p < 4; ++p) {
        uint32_t b0 = v[p * 2], b1 = v[p * 2 + 1];
        uint32_t h0 = f32_to_bf16(((float)((b0 >> 4) & 15u) - zh) * sh);
        uint32_t h1 = f32_to_bf16(((float)((b1 >> 4) & 15u) - zh) * sh);
        uint32_t l0 = f32_to_bf16(((float)(b0 & 15u) - zl) * sl);
        uint32_t l1 = f32_to_bf16(((float)(b1 & 15u) - zl) * sl);
        hw[p] = h0 | (h1 << 16);
        lw[p] = l0 | (l1 << 16);
    }
    uint4 hv = {hw[0], hw[1], hw[2], hw[3]};
    uint4 lv = {lw[0], lw[1], lw[2], lw[3]};
    *(uint4*)&Wb[(size_t)o * KD + i0]          = hv;
    *(uint4*)&Wb[(size_t)(o + 2048) * KD + i0] = lv;
}

__global__ void xc_kernel(const float* __restrict__ x, uint16_t* __restrict__ xb) {
    int t = blockIdx.x * 256 + threadIdx.x;
    const float4* xp = (const float4*)x;
    float4 a = xp[t * 2], b = xp[t * 2 + 1];
    uint4 o;
    o.x = f32_to_bf16(a.x) | (f32_to_bf16(a.y) << 16);
    o.y = f32_to_bf16(a.z) | (f32_to_bf16(a.w) << 16);
    o.z = f32_to_bf16(b.x) | (f32_to_bf16(b.y) << 16);
    o.w = f32_to_bf16(b.z) | (f32_to_bf16(b.w) << 16);
    ((uint4*)xb)[t] = o;
}

// ---------------------------------------------------------------------------
// GEMM = R11 base (best measured: 256x256 tile, BK=64, 16 waves of 64x64 @
// 1024 thr, one barrier/tile, counted lgkm split, 0 bank conflicts) with the
// main loop UNROLLED x2 so buffer parity P/Q are literals: all LDS addresses
// become loop-invariant (hoisted), stage pointers strength-reduce (+= BK).
// Mechanism: removes address-VALU from the serial read window (the concrete
// difference vs m201's "2 K-tiles/iter" template).
// ---------------------------------------------------------------------------
#define BAR()  asm volatile("s_barrier" ::: "memory")
#define LGKM(N) do { asm volatile("s_waitcnt lgkmcnt(" #N ")" ::: "memory"); \
                     __builtin_amdgcn_sched_barrier(0); } while (0)
#define VM(N)  asm volatile("s_waitcnt vmcnt(" #N ")" ::: "memory")

#define RGN(BUF, MAT, KH) ((((BUF) * 2 + (MAT)) * 2 + (KH)) * 8192)

#define RD_A(DST, P, KH) do {                                                         \
    const uint16_t* _r = lds + RGN(P, 0, KH);                                         \
    _Pragma("unroll")                                                                 \
    for (int m = 0; m < 4; ++m)                                                       \
        DST[m] = *(const bf16x8*)&_r[(wr * 64 + m * 16 + lr) * 32 + sx * 8];          \
} while (0)

#define RD_B(DST, P, KH) do {                                                         \
    const uint16_t* _r = lds + RGN(P, 1, KH);                                         \
    _Pragma("unroll")                                                                 \
    for (int n = 0; n < 4; ++n)                                                       \
        DST[n] = *(const bf16x8*)&_r[(wc * 64 + n * 16 + lr) * 32 + sx * 8];          \
} while (0)

#define MFQ(AS, BS) do {                                                              \
    __builtin_amdgcn_s_setprio(1);                                                    \
    _Pragma("unroll")                                                                 \
    for (int m = 0; m < 4; ++m)                                                       \
    _Pragma("unroll")                                                                 \
    for (int n = 0; n < 4; ++n)                                                       \
        acc[m][n] = __builtin_amdgcn_mfma_f32_16x16x32_bf16(                          \
            AS[m], BS[n], acc[m][n], 0, 0, 0);                                        \
    __builtin_amdgcn_s_setprio(0);                                                    \
} while (0)

// one K-tile: P = read buffer (literal), Q = stage buffer (literal)
#define TILE(P, Q, DOSTAGE) do {                                                      \
    if (DOSTAGE) {                                                                    \
        GLDS16(Ast,      lds + RGN(Q, 0, 0) + tid * 8);                               \
        GLDS16(Bst,      lds + RGN(Q, 1, 0) + tid * 8);                               \
        GLDS16(Ast + 32, lds + RGN(Q, 0, 1) + tid * 8);                               \
        GLDS16(Bst + 32, lds + RGN(Q, 1, 1) + tid * 8);                               \
        Ast += BK; Bst += BK;                                                         \
    }                                                                                 \
    RD_A(a0, P, 0); RD_B(b0, P, 0); RD_A(a1, P, 1);                                   \
    LGKM(4);                                                                          \
    MFQ(a0, b0);                                                                      \
    RD_B(b1, P, 1);                                                                   \
    LGKM(0);                                                                          \
    MFQ(a1, b1);                                                                      \
    VM(0);                                                                            \
    BAR();                                                                            \
} while (0)

__global__ __launch_bounds__(1024, 4)
void gemm_kernel(const uint16_t* __restrict__ A,
                 const uint16_t* __restrict__ B,
                 float* __restrict__ C) {
    __shared__ uint16_t lds[65536];   // 128 KiB: [2 buf][2 mat][2 kh][256][32]

    const int tid  = threadIdx.x;
    const int wave = tid >> 6;
    const int lane = tid & 63;
    const int wr = wave >> 2;                  // 0..3
    const int wc = wave & 3;                   // 0..3
    const int lr = lane & 15;
    const int ls = lane >> 4;
    const int sx = ls ^ ((lr >> 1) & 3);              // verified read swizzle
    const int sslot = (tid & 3) ^ ((tid >> 3) & 3);   // stage source pre-swizzle
    const int grow  = tid >> 2;                       // 0..255 staging row

    // XCD-aware swizzle: 256 wgs, 8 XCDs, 32 contiguous tiles per XCD
    int bid = blockIdx.x;
    int wg = (bid & 7) * 32 + (bid >> 3);
    const int bm0 = (wg >> 4) * 256;
    const int bn0 = (wg & 15) * 256;

    // staging pointers (strength-reduced by += BK per tile)
    const uint16_t* Ast = A + (size_t)(bm0 + grow) * KD + sslot * 8;
    const uint16_t* Bst = B + (size_t)(bn0 + grow) * KD + sslot * 8;

    f32x4 acc[4][4];
#pragma unroll
    for (int m = 0; m < 4; ++m)
#pragma unroll
        for (int n = 0; n < 4; ++n) {
            f32x4 z = {0.f, 0.f, 0.f, 0.f};
            acc[m][n] = z;
        }

    bf16x8 a0[4], b0[4], a1[4], b1[4];

    // prologue: stage tile 0 -> buf0, drain, barrier
    GLDS16(Ast,      lds + RGN(0, 0, 0) + tid * 8);
    GLDS16(Bst,      lds + RGN(0, 1, 0) + tid * 8);
    GLDS16(Ast + 32, lds + RGN(0, 0, 1) + tid * 8);
    GLDS16(Bst + 32, lds + RGN(0, 1, 1) + tid * 8);
    Ast += BK; Bst += BK;
    VM(0);
    BAR();

    // tiles 0..61 as 31 static pairs; then tile 62; tail tile 63
#pragma unroll 1
    for (int it = 0; it < 31; ++it) {
        TILE(0, 1, 1);
        TILE(1, 0, 1);
    }
    TILE(0, 1, 1);          // tile 62, stages tile 63 -> buf1
    // tail tile 63 (buf1): reads only, no trailing sync
    {
        RD_A(a0, 1, 0); RD_B(b0, 1, 0); RD_A(a1, 1, 1);
        LGKM(4);
        MFQ(a0, b0);
        RD_B(b1, 1, 1);
        LGKM(0);
        MFQ(a1, b1);
    }

    // epilogue: D layout col=lane&15, row=(lane>>4)*4+r  [m89/m91]
    const int r0 = ls * 4;
#pragma unroll
    for (int m = 0; m < 4; ++m)
#pragma unroll
        for (int n = 0; n < 4; ++n)
#pragma unroll
            for (int r = 0; r < 4; ++r) {
                int row = bm0 + wr * 64 + m * 16 + r0 + r;
                int col = bn0 + wc * 64 + n * 16 + lr;
                C[(size_t)row * ND + col] = acc[m][n][r];
            }
}

extern "C" void kernel_launch(void* const* d_in, const int* in_sizes, int n_in,
                              void* d_out, int out_size, void* d_ws, size_t ws_size,
                              hipStream_t stream) {
    const float* x     = (const float*)d_in[0];
    const int*   Wq    = (const int*)d_in[1];   // uint8 pushed as int32
    const float* scale = (const float*)d_in[2];
    const float* zero  = (const float*)d_in[3];
    float* out = (float*)d_out;

    uint16_t* Wb = (uint16_t*)d_ws;                                     // 32 MB
    uint16_t* xb = (uint16_t*)((char*)d_ws + (size_t)32 * 1024 * 1024); // 32 MB

    hipLaunchKernelGGL(dq_kernel, dim3(4096), dim3(256), 0, stream, Wq, scale, zero, Wb);
    hipLaunchKernelGGL(xc_kernel, dim3(8192), dim3(256), 0, stream, x, xb);
    hipLaunchKernelGGL(gemm_kernel, dim3(256), dim3(1024), 0, stream, xb, Wb, out);
}